// Round 4
// baseline (1050.667 us; speedup 1.0000x reference)
//
#include <hip/hip_runtime.h>
#include <hip/hip_bf16.h>

// Swin block: LN1 -> shift+window -> QKV -> window attention -> proj(+reverse,+residual)
// -> LN2 -> MLP(GELU) -> residual.  All GEMMs bf16 MFMA 16x16x32, f32 accum.
//
// R4: mlp_fused rewritten — 512 thr / 8 waves (2x4 wave grid, 32-token x 32/64-col
// wave tiles), cross-barrier register prefetch of W1/W2 fragments, sigmoid-form
// GELU (1 __expf) instead of erff.  R3 profile: mlp 403us, MfmaUtil 14%,
// VALU 25%, occ 23% -> latency/serialization bound, phases cold after barriers.

typedef __attribute__((ext_vector_type(8))) short bf16x8;
typedef __attribute__((ext_vector_type(4))) float f32x4;

__device__ __forceinline__ unsigned short f2bf(float f) {
  union { float f; unsigned u; } v; v.f = f;
  unsigned r = v.u + 0x7fffu + ((v.u >> 16) & 1u);
  return (unsigned short)(r >> 16);
}

__device__ __forceinline__ float gelu_f(float h) {
  // 0.5h(1+tanh(c1(h+c2 h^3))) == h * sigmoid(2*c1*(h+c2*h^3)); max err ~1e-3
  const float t0 = h * h;
  const float y2 = h * fmaf(-0.0713548163f, t0, -1.5957691216f);  // -2*c1*(h+c2h^3)/h
  const float e = __expf(y2);
  return h / (1.f + e);
}

__device__ __forceinline__ void gload_lds16(const unsigned short* g, void* l) {
  __builtin_amdgcn_global_load_lds(
      (const __attribute__((address_space(1))) unsigned int*)g,
      (__attribute__((address_space(3))) unsigned int*)l, 16, 0, 0);
}

// ---------------- weight transpose-convert: src f32 [K][N] -> dst bf16 [N][K]
__global__ __launch_bounds__(256) void wt_transpose(const float* __restrict__ src,
                                                    unsigned short* __restrict__ dst,
                                                    int K, int N, int total) {
  int e = blockIdx.x * 256 + threadIdx.x;
  if (e >= total) return;
  int n = e / K, k = e - n * K;
  dst[e] = f2bf(src[k * N + n]);
}

// ---------------- LN1 + cyclic shift + window partition. One wave per token.
__global__ __launch_bounds__(256) void ln1_win(const float* __restrict__ x,
                                               const float* __restrict__ g,
                                               const float* __restrict__ b,
                                               unsigned short* __restrict__ hw) {
  const int wv = threadIdx.x >> 6, ln = threadIdx.x & 63;
  const int r = blockIdx.x * 4 + wv;           // window-order token
  const int bw = r >> 6, n = r & 63;
  const int bb = bw >> 8, wi = (bw >> 4) & 15, wj = bw & 15;
  const int sh = (wi * 8 + (n >> 3) + 4) & 127;
  const int sw = (wj * 8 + (n & 7) + 4) & 127;
  const long src = ((long)bb * 16384 + sh * 128 + sw) * 256;
  float4 v = *(const float4*)(x + src + ln * 4);
  float s = v.x + v.y + v.z + v.w;
  float q = v.x * v.x + v.y * v.y + v.z * v.z + v.w * v.w;
#pragma unroll
  for (int m = 1; m < 64; m <<= 1) { s += __shfl_xor(s, m); q += __shfl_xor(q, m); }
  const float mu = s * (1.f / 256.f);
  const float rstd = rsqrtf(q * (1.f / 256.f) - mu * mu + 1e-5f);
  const int c = ln * 4;
  ushort4 o;
  o.x = f2bf((v.x - mu) * rstd * g[c + 0] + b[c + 0]);
  o.y = f2bf((v.y - mu) * rstd * g[c + 1] + b[c + 1]);
  o.z = f2bf((v.z - mu) * rstd * g[c + 2] + b[c + 2]);
  o.w = f2bf((v.w - mu) * rstd * g[c + 3] + b[c + 3]);
  *(ushort4*)(hw + (long)r * 256 + c) = o;
}

// ---------------- QKV GEMM: [M=131072][K=256] x [N=768] -> qkv bf16
__global__ __launch_bounds__(256) void gemm_qkv(const unsigned short* __restrict__ A,
                                                const unsigned short* __restrict__ Bt,
                                                const float* __restrict__ qb,
                                                const float* __restrict__ kvb,
                                                unsigned short* __restrict__ out) {
  __shared__ char lds[32768];
  char* la = lds; char* lb = lds + 16384;
  const int tid = threadIdx.x, wv = tid >> 6, ln = tid & 63;
  const int tn = blockIdx.x, tm = blockIdx.y;
  const long a_base = (long)tm * 128 * 256;
  const long b_base = (long)tn * 128 * 256;
  const int wr = (wv >> 1) * 64, wc = (wv & 1) * 64;
  f32x4 acc[4][4] = {};
  for (int ks = 0; ks < 4; ++ks) {
    const int k0 = ks * 64;
    __syncthreads();
#pragma unroll
    for (int it = 0; it < 4; ++it) {
      int d = wv * 4096 + it * 1024 + ln * 16;
      int row = d >> 7;
      int seg = ((d >> 4) & 7) ^ (row & 7);        // pre-swizzled source (m173)
      gload_lds16(A + a_base + row * 256 + k0 + seg * 8, la + wv * 4096 + it * 1024);
      gload_lds16(Bt + b_base + row * 256 + k0 + seg * 8, lb + wv * 4096 + it * 1024);
    }
    __syncthreads();
#pragma unroll
    for (int kk = 0; kk < 2; ++kk) {
      bf16x8 af[4], bfr[4];
      const int kb = (kk * 32 + (ln >> 4) * 8) * 2;
#pragma unroll
      for (int i = 0; i < 4; ++i) {
        int ra = wr + i * 16 + (ln & 15);
        af[i] = *(const bf16x8*)(la + ra * 128 + (kb ^ ((ra & 7) << 4)));
        int rb = wc + i * 16 + (ln & 15);
        bfr[i] = *(const bf16x8*)(lb + rb * 128 + (kb ^ ((rb & 7) << 4)));
      }
#pragma unroll
      for (int i = 0; i < 4; ++i)
#pragma unroll
        for (int j = 0; j < 4; ++j)
          acc[i][j] = __builtin_amdgcn_mfma_f32_16x16x32_bf16(af[i], bfr[j], acc[i][j], 0, 0, 0);
    }
  }
#pragma unroll
  for (int j = 0; j < 4; ++j) {
    const int col = tn * 128 + wc + j * 16 + (ln & 15);
    const float bias = (col < 256) ? qb[col] : kvb[col - 256];
#pragma unroll
    for (int i = 0; i < 4; ++i) {
      const int r0 = tm * 128 + wr + i * 16 + (ln >> 4) * 4;
#pragma unroll
      for (int rg = 0; rg < 4; ++rg)
        out[(long)(r0 + rg) * 768 + col] = f2bf(acc[i][j][rg] + bias);
    }
  }
}

// ---------------- windowed attention: 1 wave handles 1 window x 2 heads
__global__ __launch_bounds__(64) void attn_win(const unsigned short* __restrict__ qkv,
                                               const float* __restrict__ rpb,
                                               unsigned short* __restrict__ out) {
  __shared__ char lds[17408];                     // vt [64][72] u16 (9216B) + P 8192B
  unsigned short* vt = (unsigned short*)lds;
  char* pl = lds + 9216;
  const int ln = threadIdx.x;
  const int bw = blockIdx.x >> 2, hp = blockIdx.x & 3;
  const long base = (long)bw * 64 * 768;
  // stage V (2 heads, 64 cols) transposed into LDS
#pragma unroll
  for (int it = 0; it < 8; ++it) {
    bf16x8 v = *(const bf16x8*)(qkv + base + (long)ln * 768 + 512 + hp * 64 + it * 8);
#pragma unroll
    for (int u = 0; u < 8; ++u) vt[(it * 8 + u) * 72 + ln] = (unsigned short)v[u];
  }
  __syncthreads();
  const int wi = (bw >> 4) & 15, wj = bw & 15;
  for (int hh = 0; hh < 2; ++hh) {
    const int h = hp * 2 + hh;
    f32x4 s[4][4] = {};
    {
      bf16x8 qf[4], kf[4];
      const int dk = (ln >> 4) * 8;
#pragma unroll
      for (int i = 0; i < 4; ++i) {
        const long rq = base + (long)(i * 16 + (ln & 15)) * 768;
        qf[i] = *(const bf16x8*)(qkv + rq + h * 32 + dk);
        kf[i] = *(const bf16x8*)(qkv + rq + 256 + h * 32 + dk);
      }
#pragma unroll
      for (int i = 0; i < 4; ++i)
#pragma unroll
        for (int j = 0; j < 4; ++j)
          s[i][j] = __builtin_amdgcn_mfma_f32_16x16x32_bf16(qf[i], kf[j], s[i][j], 0, 0, 0);
    }
    // scale + rel-pos bias + shift mask
#pragma unroll
    for (int i = 0; i < 4; ++i)
#pragma unroll
      for (int rg = 0; rg < 4; ++rg) {
        const int n = i * 16 + (ln >> 4) * 4 + rg;
        const int ni = n >> 3, nj = n & 7;
        const int rn = (wi < 15) ? 0 : ((ni < 4) ? 1 : 2);
        const int cn = (wj < 15) ? 0 : ((nj < 4) ? 1 : 2);
#pragma unroll
        for (int j = 0; j < 4; ++j) {
          const int m = j * 16 + (ln & 15);
          const int mi = m >> 3, mj = m & 7;
          const float bias = rpb[((ni - mi + 7) * 15 + (nj - mj + 7)) * 8 + h];
          const int rm = (wi < 15) ? 0 : ((mi < 4) ? 1 : 2);
          const int cm = (wj < 15) ? 0 : ((mj < 4) ? 1 : 2);
          const float msk = ((rn * 3 + cn) != (rm * 3 + cm)) ? -100.f : 0.f;
          s[i][j][rg] = s[i][j][rg] * 0.17677669529663687f + bias + msk;
        }
      }
    // row softmax (rows live in 16-lane groups)
#pragma unroll
    for (int i = 0; i < 4; ++i)
#pragma unroll
      for (int rg = 0; rg < 4; ++rg) {
        float mx = fmaxf(fmaxf(s[i][0][rg], s[i][1][rg]), fmaxf(s[i][2][rg], s[i][3][rg]));
        mx = fmaxf(mx, __shfl_xor(mx, 1));
        mx = fmaxf(mx, __shfl_xor(mx, 2));
        mx = fmaxf(mx, __shfl_xor(mx, 4));
        mx = fmaxf(mx, __shfl_xor(mx, 8));
        float sum = 0.f;
#pragma unroll
        for (int j = 0; j < 4; ++j) { float e = __expf(s[i][j][rg] - mx); s[i][j][rg] = e; sum += e; }
        sum += __shfl_xor(sum, 1);
        sum += __shfl_xor(sum, 2);
        sum += __shfl_xor(sum, 4);
        sum += __shfl_xor(sum, 8);
        const float inv = 1.f / sum;
#pragma unroll
        for (int j = 0; j < 4; ++j) s[i][j][rg] *= inv;
      }
    // P -> LDS (XOR swizzled)
#pragma unroll
    for (int i = 0; i < 4; ++i)
#pragma unroll
      for (int rg = 0; rg < 4; ++rg) {
        const int n = i * 16 + (ln >> 4) * 4 + rg;
#pragma unroll
        for (int j = 0; j < 4; ++j) {
          const int m = j * 16 + (ln & 15);
          *(unsigned short*)(pl + n * 128 + ((m * 2) ^ ((n & 7) << 4))) = f2bf(s[i][j][rg]);
        }
      }
    __syncthreads();
    // PV
    f32x4 o[4][2] = {};
#pragma unroll
    for (int kk = 0; kk < 2; ++kk) {
      const int km = kk * 32 + (ln >> 4) * 8;
      bf16x8 pa[4], vb[2];
#pragma unroll
      for (int i = 0; i < 4; ++i) {
        const int n = i * 16 + (ln & 15);
        pa[i] = *(const bf16x8*)(pl + n * 128 + ((km * 2) ^ ((n & 7) << 4)));
      }
#pragma unroll
      for (int j = 0; j < 2; ++j)
        vb[j] = *(const bf16x8*)((const char*)vt + ((hh * 32 + j * 16 + (ln & 15)) * 72 + km) * 2);
#pragma unroll
      for (int i = 0; i < 4; ++i)
#pragma unroll
        for (int j = 0; j < 2; ++j)
          o[i][j] = __builtin_amdgcn_mfma_f32_16x16x32_bf16(pa[i], vb[j], o[i][j], 0, 0, 0);
    }
#pragma unroll
    for (int i = 0; i < 4; ++i)
#pragma unroll
      for (int j = 0; j < 2; ++j)
#pragma unroll
        for (int rg = 0; rg < 4; ++rg) {
          const int n = i * 16 + (ln >> 4) * 4 + rg;
          const int d = j * 16 + (ln & 15);
          out[(long)(bw * 64 + n) * 256 + h * 32 + d] = f2bf(o[i][j][rg]);
        }
    __syncthreads();
  }
}

// ---------------- proj GEMM + window reverse + unshift + residual (f32 x1)
__global__ __launch_bounds__(256) void gemm_proj(const unsigned short* __restrict__ A,
                                                 const unsigned short* __restrict__ Bt,
                                                 const float* __restrict__ pb,
                                                 const float* __restrict__ x,
                                                 float* __restrict__ x1) {
  __shared__ char lds[32768];
  char* la = lds; char* lb = lds + 16384;
  const int tid = threadIdx.x, wv = tid >> 6, ln = tid & 63;
  const int tn = blockIdx.x, tm = blockIdx.y;
  const long a_base = (long)tm * 128 * 256;
  const long b_base = (long)tn * 128 * 256;
  const int wr = (wv >> 1) * 64, wc = (wv & 1) * 64;
  f32x4 acc[4][4] = {};
  for (int ks = 0; ks < 4; ++ks) {
    const int k0 = ks * 64;
    __syncthreads();
#pragma unroll
    for (int it = 0; it < 4; ++it) {
      int d = wv * 4096 + it * 1024 + ln * 16;
      int row = d >> 7;
      int seg = ((d >> 4) & 7) ^ (row & 7);
      gload_lds16(A + a_base + row * 256 + k0 + seg * 8, la + wv * 4096 + it * 1024);
      gload_lds16(Bt + b_base + row * 256 + k0 + seg * 8, lb + wv * 4096 + it * 1024);
    }
    __syncthreads();
#pragma unroll
    for (int kk = 0; kk < 2; ++kk) {
      bf16x8 af[4], bfr[4];
      const int kb = (kk * 32 + (ln >> 4) * 8) * 2;
#pragma unroll
      for (int i = 0; i < 4; ++i) {
        int ra = wr + i * 16 + (ln & 15);
        af[i] = *(const bf16x8*)(la + ra * 128 + (kb ^ ((ra & 7) << 4)));
        int rb = wc + i * 16 + (ln & 15);
        bfr[i] = *(const bf16x8*)(lb + rb * 128 + (kb ^ ((rb & 7) << 4)));
      }
#pragma unroll
      for (int i = 0; i < 4; ++i)
#pragma unroll
        for (int j = 0; j < 4; ++j)
          acc[i][j] = __builtin_amdgcn_mfma_f32_16x16x32_bf16(af[i], bfr[j], acc[i][j], 0, 0, 0);
    }
  }
#pragma unroll
  for (int i = 0; i < 4; ++i) {
    const int R0 = tm * 128 + wr + i * 16 + (ln >> 4) * 4;
#pragma unroll
    for (int rg = 0; rg < 4; ++rg) {
      const int R = R0 + rg;
      const int bw = R >> 6, n = R & 63;
      const int bb = bw >> 8, wi = (bw >> 4) & 15, wj = bw & 15;
      const int sh = (wi * 8 + (n >> 3) + 4) & 127;
      const int sw = (wj * 8 + (n & 7) + 4) & 127;
      const long dst = ((long)bb * 16384 + sh * 128 + sw) * 256;
#pragma unroll
      for (int j = 0; j < 4; ++j) {
        const int col = tn * 128 + wc + j * 16 + (ln & 15);
        x1[dst + col] = x[dst + col] + acc[i][j][rg] + pb[col];
      }
    }
  }
}

// ---------------- fused LN2 + fc1 + GELU + fc2 + residual (f32 out)
// 512 thr = 8 waves in 2(m) x 4(n); per chunk (128 hidden):
//   fc1: wave tile 32tok x 32hid, hc[2][2];  fc2: 32tok x 64out, acc[2][4]
__global__ __launch_bounds__(512, 4) void mlp_fused(const float* __restrict__ x1,
                                                    const float* __restrict__ g2,
                                                    const float* __restrict__ b2,
                                                    const unsigned short* __restrict__ w1t,
                                                    const float* __restrict__ fb1,
                                                    const unsigned short* __restrict__ w2t,
                                                    const float* __restrict__ fb2,
                                                    float* __restrict__ out) {
  __shared__ char lds[49152];                 // A_ln [64][256] 32KB + H [64][128] 16KB
  char* hl = lds + 32768;
  const int tid = threadIdx.x, ln = tid & 63;
  const int wv = tid >> 6, wm = wv >> 2, wn = wv & 3;
  const long rbase = (long)blockIdx.x * 64;
  // ---- LN2 stage: 8 threads per token, 32 cols each
  {
    const int t = tid >> 3, q = tid & 7;
    const float* xr = x1 + (rbase + t) * 256 + q * 32;
    float4 v[8];
    float s = 0.f, sq = 0.f;
#pragma unroll
    for (int u = 0; u < 8; ++u) {
      v[u] = *(const float4*)(xr + u * 4);
      s += v[u].x + v[u].y + v[u].z + v[u].w;
      sq += v[u].x * v[u].x + v[u].y * v[u].y + v[u].z * v[u].z + v[u].w * v[u].w;
    }
    s += __shfl_xor(s, 1); s += __shfl_xor(s, 2); s += __shfl_xor(s, 4);
    sq += __shfl_xor(sq, 1); sq += __shfl_xor(sq, 2); sq += __shfl_xor(sq, 4);
    const float mu = s * (1.f / 256.f);
    const float rstd = rsqrtf(sq * (1.f / 256.f) - mu * mu + 1e-5f);
#pragma unroll
    for (int c8 = 0; c8 < 4; ++c8) {
      bf16x8 o;
#pragma unroll
      for (int u = 0; u < 8; ++u) {
        const int col = q * 32 + c8 * 8 + u;
        const float fv = ((&v[c8 * 2 + (u >> 2)].x)[u & 3] - mu) * rstd * g2[col] + b2[col];
        o[u] = (short)f2bf(fv);
      }
      *(bf16x8*)(lds + t * 512 + (((q * 32 + c8 * 8) * 2) ^ ((t & 7) << 4))) = o;
    }
  }
  // prefetch W1(ch=0, ks=0) before the barrier (no LDS dependency)
  bf16x8 wf_pre[2];
#pragma unroll
  for (int j = 0; j < 2; ++j)
    wf_pre[j] = *(const bf16x8*)(w1t + (long)(wn * 32 + j * 16 + (ln & 15)) * 256 + (ln >> 4) * 8);
  __syncthreads();
  f32x4 acc[2][4] = {};
  for (int ch = 0; ch < 8; ++ch) {
    f32x4 hc[2][2] = {};
#pragma unroll
    for (int ks = 0; ks < 8; ++ks) {
      bf16x8 af[2], wf[2];
      if (ks == 0) { wf[0] = wf_pre[0]; wf[1] = wf_pre[1]; }
      else {
#pragma unroll
        for (int j = 0; j < 2; ++j)
          wf[j] = *(const bf16x8*)(w1t + (long)(ch * 128 + wn * 32 + j * 16 + (ln & 15)) * 256 +
                                   ks * 32 + (ln >> 4) * 8);
      }
      const int kb = (ks * 32 + (ln >> 4) * 8) * 2;
#pragma unroll
      for (int i = 0; i < 2; ++i) {
        const int ra = wm * 32 + i * 16 + (ln & 15);
        af[i] = *(const bf16x8*)(lds + ra * 512 + (kb ^ ((ra & 7) << 4)));
      }
#pragma unroll
      for (int i = 0; i < 2; ++i)
#pragma unroll
        for (int j = 0; j < 2; ++j)
          hc[i][j] = __builtin_amdgcn_mfma_f32_16x16x32_bf16(af[i], wf[j], hc[i][j], 0, 0, 0);
    }
    __syncthreads();            // H free: all waves finished fc2 reads of prev chunk
#pragma unroll
    for (int i = 0; i < 2; ++i)
#pragma unroll
      for (int j = 0; j < 2; ++j)
#pragma unroll
        for (int rg = 0; rg < 4; ++rg) {
          const int t = wm * 32 + i * 16 + (ln >> 4) * 4 + rg;
          const int cH = wn * 32 + j * 16 + (ln & 15);
          const float val = hc[i][j][rg] + fb1[ch * 128 + cH];
          *(unsigned short*)(hl + t * 256 + ((cH * 2) ^ ((t & 7) << 4))) = f2bf(gelu_f(val));
        }
    // cross-barrier prefetch: W2(kk=0) of this chunk, W1(ks=0) of next chunk
    bf16x8 wb_pre[4];
#pragma unroll
    for (int j = 0; j < 4; ++j)
      wb_pre[j] = *(const bf16x8*)(w2t + (long)(wn * 64 + j * 16 + (ln & 15)) * 1024 +
                                   ch * 128 + (ln >> 4) * 8);
    if (ch < 7) {
#pragma unroll
      for (int j = 0; j < 2; ++j)
        wf_pre[j] = *(const bf16x8*)(w1t + (long)((ch + 1) * 128 + wn * 32 + j * 16 + (ln & 15)) * 256 +
                                     (ln >> 4) * 8);
    }
    __syncthreads();            // H ready
#pragma unroll
    for (int kk = 0; kk < 4; ++kk) {
      bf16x8 ha[2], wb[4];
      if (kk == 0) { wb[0] = wb_pre[0]; wb[1] = wb_pre[1]; wb[2] = wb_pre[2]; wb[3] = wb_pre[3]; }
      else {
#pragma unroll
        for (int j = 0; j < 4; ++j)
          wb[j] = *(const bf16x8*)(w2t + (long)(wn * 64 + j * 16 + (ln & 15)) * 1024 +
                                   ch * 128 + kk * 32 + (ln >> 4) * 8);
      }
      const int kb2 = (kk * 32 + (ln >> 4) * 8) * 2;
#pragma unroll
      for (int i = 0; i < 2; ++i) {
        const int tt = wm * 32 + i * 16 + (ln & 15);
        ha[i] = *(const bf16x8*)(hl + tt * 256 + (kb2 ^ ((tt & 7) << 4)));
      }
#pragma unroll
      for (int i = 0; i < 2; ++i)
#pragma unroll
        for (int j = 0; j < 4; ++j)
          acc[i][j] = __builtin_amdgcn_mfma_f32_16x16x32_bf16(ha[i], wb[j], acc[i][j], 0, 0, 0);
    }
  }
  // epilogue: residual + bias, f32 store
#pragma unroll
  for (int i = 0; i < 2; ++i)
#pragma unroll
    for (int rg = 0; rg < 4; ++rg) {
      const long t = rbase + wm * 32 + i * 16 + (ln >> 4) * 4 + rg;
#pragma unroll
      for (int j = 0; j < 4; ++j) {
        const int col = wn * 64 + j * 16 + (ln & 15);
        out[t * 256 + col] = x1[t * 256 + col] + acc[i][j][rg] + fb2[col];
      }
    }
}

extern "C" void kernel_launch(void* const* d_in, const int* in_sizes, int n_in,
                              void* d_out, int out_size, void* d_ws, size_t ws_size,
                              hipStream_t stream) {
  const float* x     = (const float*)d_in[0];
  const float* g1    = (const float*)d_in[1];
  const float* b1    = (const float*)d_in[2];
  const float* qw    = (const float*)d_in[3];
  const float* qb    = (const float*)d_in[4];
  const float* kvw   = (const float*)d_in[5];
  const float* kvb   = (const float*)d_in[6];
  const float* rpb   = (const float*)d_in[7];
  const float* projw = (const float*)d_in[8];
  const float* projb = (const float*)d_in[9];
  const float* g2    = (const float*)d_in[10];
  const float* b2    = (const float*)d_in[11];
  const float* fc1w  = (const float*)d_in[12];
  const float* fc1b  = (const float*)d_in[13];
  const float* fc2w  = (const float*)d_in[14];
  const float* fc2b  = (const float*)d_in[15];

  // Workspace: weights (bf16 B^T) + qkv only  (~203 MB total)
  unsigned short* wqkv  = (unsigned short*)d_ws;            // 196608
  unsigned short* wproj = wqkv + 196608;                     // 65536
  unsigned short* wfc1  = wproj + 65536;                     // 262144
  unsigned short* wfc2  = wfc1 + 262144;                     // 262144
  unsigned short* qkv   = wfc2 + 262144;                     // 100663296 (reused: x1 f32)
  float* x1 = (float*)qkv;
  // hw [131072][256] bf16 = first half of the f32 d_out buffer (scratch);
  // overwritten by attn-out, then fully overwritten by the final f32 store.
  unsigned short* hw = (unsigned short*)d_out;

  wt_transpose<<<256, 256, 0, stream>>>(qw, wqkv, 256, 256, 65536);
  wt_transpose<<<512, 256, 0, stream>>>(kvw, wqkv + 65536, 256, 512, 131072);
  wt_transpose<<<256, 256, 0, stream>>>(projw, wproj, 256, 256, 65536);
  wt_transpose<<<1024, 256, 0, stream>>>(fc1w, wfc1, 256, 1024, 262144);
  wt_transpose<<<1024, 256, 0, stream>>>(fc2w, wfc2, 1024, 256, 262144);

  ln1_win<<<32768, 256, 0, stream>>>(x, g1, b1, hw);
  gemm_qkv<<<dim3(6, 1024), 256, 0, stream>>>(hw, wqkv, qb, kvb, qkv);
  attn_win<<<8192, 64, 0, stream>>>(qkv, rpb, hw);           // hw now = attention output
  gemm_proj<<<dim3(2, 1024), 256, 0, stream>>>(hw, wproj, projb, x, x1);
  mlp_fused<<<2048, 512, 0, stream>>>(x1, g2, b2, wfc1, fc1b, wfc2, fc2b,
                                      (float*)d_out);
}

// Round 5
// 853.958 us; speedup vs baseline: 1.2303x; 1.2303x over previous
//
#include <hip/hip_runtime.h>
#include <hip/hip_bf16.h>

// Swin block: LN1 -> shift+window -> QKV -> window attention -> proj(+reverse,+residual)
// -> LN2 -> MLP(GELU) -> residual.  All GEMMs bf16 MFMA 16x16x32, f32 accum.
//
// R5: mlp_fused = R3 structure (4 waves, 403us) + (a) H double-buffer merging
// fc1(ch+1) and fc2(ch) into ONE phase -> 9 barriers instead of 16, two
// independent dep-chains per phase; (b) cheap sigmoid-form GELU (HW-validated
// in R4).  R4's 8-wave small-tile variant regressed (564us): occupancy was not
// binding; per-wave MFMA:load ratio and barrier drains are.

typedef __attribute__((ext_vector_type(8))) short bf16x8;
typedef __attribute__((ext_vector_type(4))) float f32x4;

__device__ __forceinline__ unsigned short f2bf(float f) {
  union { float f; unsigned u; } v; v.f = f;
  unsigned r = v.u + 0x7fffu + ((v.u >> 16) & 1u);
  return (unsigned short)(r >> 16);
}

__device__ __forceinline__ float gelu_f(float h) {
  // 0.5h(1+tanh(c1(h+c2 h^3))) == h * sigmoid(2*c1*(h+c2*h^3))
  const float t0 = h * h;
  const float y2 = h * fmaf(-0.0713548163f, t0, -1.5957691216f);
  const float e = __expf(y2);
  return h / (1.f + e);
}

__device__ __forceinline__ void gload_lds16(const unsigned short* g, void* l) {
  __builtin_amdgcn_global_load_lds(
      (const __attribute__((address_space(1))) unsigned int*)g,
      (__attribute__((address_space(3))) unsigned int*)l, 16, 0, 0);
}

// ---------------- weight transpose-convert: src f32 [K][N] -> dst bf16 [N][K]
__global__ __launch_bounds__(256) void wt_transpose(const float* __restrict__ src,
                                                    unsigned short* __restrict__ dst,
                                                    int K, int N, int total) {
  int e = blockIdx.x * 256 + threadIdx.x;
  if (e >= total) return;
  int n = e / K, k = e - n * K;
  dst[e] = f2bf(src[k * N + n]);
}

// ---------------- LN1 + cyclic shift + window partition. One wave per token.
__global__ __launch_bounds__(256) void ln1_win(const float* __restrict__ x,
                                               const float* __restrict__ g,
                                               const float* __restrict__ b,
                                               unsigned short* __restrict__ hw) {
  const int wv = threadIdx.x >> 6, ln = threadIdx.x & 63;
  const int r = blockIdx.x * 4 + wv;           // window-order token
  const int bw = r >> 6, n = r & 63;
  const int bb = bw >> 8, wi = (bw >> 4) & 15, wj = bw & 15;
  const int sh = (wi * 8 + (n >> 3) + 4) & 127;
  const int sw = (wj * 8 + (n & 7) + 4) & 127;
  const long src = ((long)bb * 16384 + sh * 128 + sw) * 256;
  float4 v = *(const float4*)(x + src + ln * 4);
  float s = v.x + v.y + v.z + v.w;
  float q = v.x * v.x + v.y * v.y + v.z * v.z + v.w * v.w;
#pragma unroll
  for (int m = 1; m < 64; m <<= 1) { s += __shfl_xor(s, m); q += __shfl_xor(q, m); }
  const float mu = s * (1.f / 256.f);
  const float rstd = rsqrtf(q * (1.f / 256.f) - mu * mu + 1e-5f);
  const int c = ln * 4;
  ushort4 o;
  o.x = f2bf((v.x - mu) * rstd * g[c + 0] + b[c + 0]);
  o.y = f2bf((v.y - mu) * rstd * g[c + 1] + b[c + 1]);
  o.z = f2bf((v.z - mu) * rstd * g[c + 2] + b[c + 2]);
  o.w = f2bf((v.w - mu) * rstd * g[c + 3] + b[c + 3]);
  *(ushort4*)(hw + (long)r * 256 + c) = o;
}

// ---------------- QKV GEMM: [M=131072][K=256] x [N=768] -> qkv bf16
__global__ __launch_bounds__(256) void gemm_qkv(const unsigned short* __restrict__ A,
                                                const unsigned short* __restrict__ Bt,
                                                const float* __restrict__ qb,
                                                const float* __restrict__ kvb,
                                                unsigned short* __restrict__ out) {
  __shared__ char lds[32768];
  char* la = lds; char* lb = lds + 16384;
  const int tid = threadIdx.x, wv = tid >> 6, ln = tid & 63;
  const int tn = blockIdx.x, tm = blockIdx.y;
  const long a_base = (long)tm * 128 * 256;
  const long b_base = (long)tn * 128 * 256;
  const int wr = (wv >> 1) * 64, wc = (wv & 1) * 64;
  f32x4 acc[4][4] = {};
  for (int ks = 0; ks < 4; ++ks) {
    const int k0 = ks * 64;
    __syncthreads();
#pragma unroll
    for (int it = 0; it < 4; ++it) {
      int d = wv * 4096 + it * 1024 + ln * 16;
      int row = d >> 7;
      int seg = ((d >> 4) & 7) ^ (row & 7);        // pre-swizzled source (m173)
      gload_lds16(A + a_base + row * 256 + k0 + seg * 8, la + wv * 4096 + it * 1024);
      gload_lds16(Bt + b_base + row * 256 + k0 + seg * 8, lb + wv * 4096 + it * 1024);
    }
    __syncthreads();
#pragma unroll
    for (int kk = 0; kk < 2; ++kk) {
      bf16x8 af[4], bfr[4];
      const int kb = (kk * 32 + (ln >> 4) * 8) * 2;
#pragma unroll
      for (int i = 0; i < 4; ++i) {
        int ra = wr + i * 16 + (ln & 15);
        af[i] = *(const bf16x8*)(la + ra * 128 + (kb ^ ((ra & 7) << 4)));
        int rb = wc + i * 16 + (ln & 15);
        bfr[i] = *(const bf16x8*)(lb + rb * 128 + (kb ^ ((rb & 7) << 4)));
      }
#pragma unroll
      for (int i = 0; i < 4; ++i)
#pragma unroll
        for (int j = 0; j < 4; ++j)
          acc[i][j] = __builtin_amdgcn_mfma_f32_16x16x32_bf16(af[i], bfr[j], acc[i][j], 0, 0, 0);
    }
  }
#pragma unroll
  for (int j = 0; j < 4; ++j) {
    const int col = tn * 128 + wc + j * 16 + (ln & 15);
    const float bias = (col < 256) ? qb[col] : kvb[col - 256];
#pragma unroll
    for (int i = 0; i < 4; ++i) {
      const int r0 = tm * 128 + wr + i * 16 + (ln >> 4) * 4;
#pragma unroll
      for (int rg = 0; rg < 4; ++rg)
        out[(long)(r0 + rg) * 768 + col] = f2bf(acc[i][j][rg] + bias);
    }
  }
}

// ---------------- windowed attention: 1 wave handles 1 window x 2 heads
__global__ __launch_bounds__(64) void attn_win(const unsigned short* __restrict__ qkv,
                                               const float* __restrict__ rpb,
                                               unsigned short* __restrict__ out) {
  __shared__ char lds[17408];                     // vt [64][72] u16 (9216B) + P 8192B
  unsigned short* vt = (unsigned short*)lds;
  char* pl = lds + 9216;
  const int ln = threadIdx.x;
  const int bw = blockIdx.x >> 2, hp = blockIdx.x & 3;
  const long base = (long)bw * 64 * 768;
  // stage V (2 heads, 64 cols) transposed into LDS
#pragma unroll
  for (int it = 0; it < 8; ++it) {
    bf16x8 v = *(const bf16x8*)(qkv + base + (long)ln * 768 + 512 + hp * 64 + it * 8);
#pragma unroll
    for (int u = 0; u < 8; ++u) vt[(it * 8 + u) * 72 + ln] = (unsigned short)v[u];
  }
  __syncthreads();
  const int wi = (bw >> 4) & 15, wj = bw & 15;
  for (int hh = 0; hh < 2; ++hh) {
    const int h = hp * 2 + hh;
    f32x4 s[4][4] = {};
    {
      bf16x8 qf[4], kf[4];
      const int dk = (ln >> 4) * 8;
#pragma unroll
      for (int i = 0; i < 4; ++i) {
        const long rq = base + (long)(i * 16 + (ln & 15)) * 768;
        qf[i] = *(const bf16x8*)(qkv + rq + h * 32 + dk);
        kf[i] = *(const bf16x8*)(qkv + rq + 256 + h * 32 + dk);
      }
#pragma unroll
      for (int i = 0; i < 4; ++i)
#pragma unroll
        for (int j = 0; j < 4; ++j)
          s[i][j] = __builtin_amdgcn_mfma_f32_16x16x32_bf16(qf[i], kf[j], s[i][j], 0, 0, 0);
    }
    // scale + rel-pos bias + shift mask
#pragma unroll
    for (int i = 0; i < 4; ++i)
#pragma unroll
      for (int rg = 0; rg < 4; ++rg) {
        const int n = i * 16 + (ln >> 4) * 4 + rg;
        const int ni = n >> 3, nj = n & 7;
        const int rn = (wi < 15) ? 0 : ((ni < 4) ? 1 : 2);
        const int cn = (wj < 15) ? 0 : ((nj < 4) ? 1 : 2);
#pragma unroll
        for (int j = 0; j < 4; ++j) {
          const int m = j * 16 + (ln & 15);
          const int mi = m >> 3, mj = m & 7;
          const float bias = rpb[((ni - mi + 7) * 15 + (nj - mj + 7)) * 8 + h];
          const int rm = (wi < 15) ? 0 : ((mi < 4) ? 1 : 2);
          const int cm = (wj < 15) ? 0 : ((mj < 4) ? 1 : 2);
          const float msk = ((rn * 3 + cn) != (rm * 3 + cm)) ? -100.f : 0.f;
          s[i][j][rg] = s[i][j][rg] * 0.17677669529663687f + bias + msk;
        }
      }
    // row softmax (rows live in 16-lane groups)
#pragma unroll
    for (int i = 0; i < 4; ++i)
#pragma unroll
      for (int rg = 0; rg < 4; ++rg) {
        float mx = fmaxf(fmaxf(s[i][0][rg], s[i][1][rg]), fmaxf(s[i][2][rg], s[i][3][rg]));
        mx = fmaxf(mx, __shfl_xor(mx, 1));
        mx = fmaxf(mx, __shfl_xor(mx, 2));
        mx = fmaxf(mx, __shfl_xor(mx, 4));
        mx = fmaxf(mx, __shfl_xor(mx, 8));
        float sum = 0.f;
#pragma unroll
        for (int j = 0; j < 4; ++j) { float e = __expf(s[i][j][rg] - mx); s[i][j][rg] = e; sum += e; }
        sum += __shfl_xor(sum, 1);
        sum += __shfl_xor(sum, 2);
        sum += __shfl_xor(sum, 4);
        sum += __shfl_xor(sum, 8);
        const float inv = 1.f / sum;
#pragma unroll
        for (int j = 0; j < 4; ++j) s[i][j][rg] *= inv;
      }
    // P -> LDS (XOR swizzled)
#pragma unroll
    for (int i = 0; i < 4; ++i)
#pragma unroll
      for (int rg = 0; rg < 4; ++rg) {
        const int n = i * 16 + (ln >> 4) * 4 + rg;
#pragma unroll
        for (int j = 0; j < 4; ++j) {
          const int m = j * 16 + (ln & 15);
          *(unsigned short*)(pl + n * 128 + ((m * 2) ^ ((n & 7) << 4))) = f2bf(s[i][j][rg]);
        }
      }
    __syncthreads();
    // PV
    f32x4 o[4][2] = {};
#pragma unroll
    for (int kk = 0; kk < 2; ++kk) {
      const int km = kk * 32 + (ln >> 4) * 8;
      bf16x8 pa[4], vb[2];
#pragma unroll
      for (int i = 0; i < 4; ++i) {
        const int n = i * 16 + (ln & 15);
        pa[i] = *(const bf16x8*)(pl + n * 128 + ((km * 2) ^ ((n & 7) << 4)));
      }
#pragma unroll
      for (int j = 0; j < 2; ++j)
        vb[j] = *(const bf16x8*)((const char*)vt + ((hh * 32 + j * 16 + (ln & 15)) * 72 + km) * 2);
#pragma unroll
      for (int i = 0; i < 4; ++i)
#pragma unroll
        for (int j = 0; j < 2; ++j)
          o[i][j] = __builtin_amdgcn_mfma_f32_16x16x32_bf16(pa[i], vb[j], o[i][j], 0, 0, 0);
    }
#pragma unroll
    for (int i = 0; i < 4; ++i)
#pragma unroll
      for (int j = 0; j < 2; ++j)
#pragma unroll
        for (int rg = 0; rg < 4; ++rg) {
          const int n = i * 16 + (ln >> 4) * 4 + rg;
          const int d = j * 16 + (ln & 15);
          out[(long)(bw * 64 + n) * 256 + h * 32 + d] = f2bf(o[i][j][rg]);
        }
    __syncthreads();
  }
}

// ---------------- proj GEMM + window reverse + unshift + residual (f32 x1)
__global__ __launch_bounds__(256) void gemm_proj(const unsigned short* __restrict__ A,
                                                 const unsigned short* __restrict__ Bt,
                                                 const float* __restrict__ pb,
                                                 const float* __restrict__ x,
                                                 float* __restrict__ x1) {
  __shared__ char lds[32768];
  char* la = lds; char* lb = lds + 16384;
  const int tid = threadIdx.x, wv = tid >> 6, ln = tid & 63;
  const int tn = blockIdx.x, tm = blockIdx.y;
  const long a_base = (long)tm * 128 * 256;
  const long b_base = (long)tn * 128 * 256;
  const int wr = (wv >> 1) * 64, wc = (wv & 1) * 64;
  f32x4 acc[4][4] = {};
  for (int ks = 0; ks < 4; ++ks) {
    const int k0 = ks * 64;
    __syncthreads();
#pragma unroll
    for (int it = 0; it < 4; ++it) {
      int d = wv * 4096 + it * 1024 + ln * 16;
      int row = d >> 7;
      int seg = ((d >> 4) & 7) ^ (row & 7);
      gload_lds16(A + a_base + row * 256 + k0 + seg * 8, la + wv * 4096 + it * 1024);
      gload_lds16(Bt + b_base + row * 256 + k0 + seg * 8, lb + wv * 4096 + it * 1024);
    }
    __syncthreads();
#pragma unroll
    for (int kk = 0; kk < 2; ++kk) {
      bf16x8 af[4], bfr[4];
      const int kb = (kk * 32 + (ln >> 4) * 8) * 2;
#pragma unroll
      for (int i = 0; i < 4; ++i) {
        int ra = wr + i * 16 + (ln & 15);
        af[i] = *(const bf16x8*)(la + ra * 128 + (kb ^ ((ra & 7) << 4)));
        int rb = wc + i * 16 + (ln & 15);
        bfr[i] = *(const bf16x8*)(lb + rb * 128 + (kb ^ ((rb & 7) << 4)));
      }
#pragma unroll
      for (int i = 0; i < 4; ++i)
#pragma unroll
        for (int j = 0; j < 4; ++j)
          acc[i][j] = __builtin_amdgcn_mfma_f32_16x16x32_bf16(af[i], bfr[j], acc[i][j], 0, 0, 0);
    }
  }
#pragma unroll
  for (int i = 0; i < 4; ++i) {
    const int R0 = tm * 128 + wr + i * 16 + (ln >> 4) * 4;
#pragma unroll
    for (int rg = 0; rg < 4; ++rg) {
      const int R = R0 + rg;
      const int bw = R >> 6, n = R & 63;
      const int bb = bw >> 8, wi = (bw >> 4) & 15, wj = bw & 15;
      const int sh = (wi * 8 + (n >> 3) + 4) & 127;
      const int sw = (wj * 8 + (n & 7) + 4) & 127;
      const long dst = ((long)bb * 16384 + sh * 128 + sw) * 256;
#pragma unroll
      for (int j = 0; j < 4; ++j) {
        const int col = tn * 128 + wc + j * 16 + (ln & 15);
        x1[dst + col] = x[dst + col] + acc[i][j][rg] + pb[col];
      }
    }
  }
}

// ---------------- fused LN2 + fc1 + GELU + fc2 + residual (f32 out)
// 256 thr / 4 waves (R3 tiles).  H double-buffered: per chunk ONE barrier;
// phase = fc1(ch+1) [W1-global + A-LDS chains] || fc2(ch) [H-LDS + W2-global].
__global__ __launch_bounds__(256, 2) void mlp_fused(const float* __restrict__ x1,
                                                    const float* __restrict__ g2,
                                                    const float* __restrict__ b2,
                                                    const unsigned short* __restrict__ w1t,
                                                    const float* __restrict__ fb1,
                                                    const unsigned short* __restrict__ w2t,
                                                    const float* __restrict__ fb2,
                                                    float* __restrict__ out) {
  __shared__ char lds[65536];           // A_ln [64][256] 32KB | H0 16KB | H1 16KB
  char* h0 = lds + 32768;
  char* h1 = lds + 49152;
  const int tid = threadIdx.x, wv = tid >> 6, ln = tid & 63;
  const long rbase = (long)blockIdx.x * 64;
  // ---- LN2 stage (4 threads per token)
  {
    const int t = tid >> 2, q = tid & 3;
    const float* xr = x1 + (rbase + t) * 256 + q * 64;
    float4 v[16];
    float s = 0.f, sq = 0.f;
#pragma unroll
    for (int u = 0; u < 16; ++u) {
      v[u] = *(const float4*)(xr + u * 4);
      s += v[u].x + v[u].y + v[u].z + v[u].w;
      sq += v[u].x * v[u].x + v[u].y * v[u].y + v[u].z * v[u].z + v[u].w * v[u].w;
    }
    s += __shfl_xor(s, 1); s += __shfl_xor(s, 2);
    sq += __shfl_xor(sq, 1); sq += __shfl_xor(sq, 2);
    const float mu = s * (1.f / 256.f);
    const float rstd = rsqrtf(sq * (1.f / 256.f) - mu * mu + 1e-5f);
#pragma unroll
    for (int c8 = 0; c8 < 8; ++c8) {
      bf16x8 o;
#pragma unroll
      for (int u = 0; u < 8; ++u) {
        const int col = q * 64 + c8 * 8 + u;
        const float fv = ((&v[c8 * 2 + (u >> 2)].x)[u & 3] - mu) * rstd * g2[col] + b2[col];
        o[u] = (short)f2bf(fv);
      }
      *(bf16x8*)(lds + t * 512 + (((q * 64 + c8 * 8) * 2) ^ ((t & 7) << 4))) = o;
    }
  }

  f32x4 acc[4][4] = {};
  f32x4 hc[4][2];

  auto fc1_compute = [&](int ch) {
#pragma unroll
    for (int i = 0; i < 4; ++i)
#pragma unroll
      for (int j = 0; j < 2; ++j) hc[i][j] = (f32x4){0.f, 0.f, 0.f, 0.f};
#pragma unroll
    for (int ks = 0; ks < 8; ++ks) {
      bf16x8 af[4], wf[2];
#pragma unroll
      for (int j = 0; j < 2; ++j)
        wf[j] = *(const bf16x8*)(w1t + (long)(ch * 128 + wv * 32 + j * 16 + (ln & 15)) * 256 +
                                 ks * 32 + (ln >> 4) * 8);
      const int kb = (ks * 32 + (ln >> 4) * 8) * 2;
#pragma unroll
      for (int i = 0; i < 4; ++i) {
        const int ra = i * 16 + (ln & 15);
        af[i] = *(const bf16x8*)(lds + ra * 512 + (kb ^ ((ra & 7) << 4)));
      }
#pragma unroll
      for (int i = 0; i < 4; ++i)
#pragma unroll
        for (int j = 0; j < 2; ++j)
          hc[i][j] = __builtin_amdgcn_mfma_f32_16x16x32_bf16(af[i], wf[j], hc[i][j], 0, 0, 0);
    }
  };

  auto gelu_store = [&](int ch, char* hdst) {
#pragma unroll
    for (int j = 0; j < 2; ++j) {
      const int cH = wv * 32 + j * 16 + (ln & 15);
      const float fb = fb1[ch * 128 + cH];
#pragma unroll
      for (int i = 0; i < 4; ++i)
#pragma unroll
        for (int rg = 0; rg < 4; ++rg) {
          const int t = i * 16 + (ln >> 4) * 4 + rg;
          const float val = hc[i][j][rg] + fb;
          *(unsigned short*)(hdst + t * 256 + ((cH * 2) ^ ((t & 7) << 4))) = f2bf(gelu_f(val));
        }
    }
  };

  auto fc2_compute = [&](int ch, const char* hsrc) {
#pragma unroll
    for (int kk = 0; kk < 4; ++kk) {
      const int kb2 = kk * 32 + (ln >> 4) * 8;
      bf16x8 ha[4], wb[4];
#pragma unroll
      for (int j = 0; j < 4; ++j)
        wb[j] = *(const bf16x8*)(w2t + (long)(wv * 64 + j * 16 + (ln & 15)) * 1024 +
                                 ch * 128 + kb2);
#pragma unroll
      for (int i = 0; i < 4; ++i) {
        const int tt = i * 16 + (ln & 15);
        ha[i] = *(const bf16x8*)(hsrc + tt * 256 + ((kb2 * 2) ^ ((tt & 7) << 4)));
      }
#pragma unroll
      for (int i = 0; i < 4; ++i)
#pragma unroll
        for (int j = 0; j < 4; ++j)
          acc[i][j] = __builtin_amdgcn_mfma_f32_16x16x32_bf16(ha[i], wb[j], acc[i][j], 0, 0, 0);
    }
  };

  __syncthreads();              // A_ln ready
  fc1_compute(0);
  gelu_store(0, h0);
  __syncthreads();              // H0 ready
#pragma unroll 2
  for (int ch = 0; ch < 8; ++ch) {
    char* hr = (ch & 1) ? h1 : h0;
    char* hw2 = (ch & 1) ? h0 : h1;
    if (ch < 7) fc1_compute(ch + 1);   // indep chain: W1 global + A LDS
    fc2_compute(ch, hr);               // indep chain: H LDS + W2 global
    if (ch < 7) {
      gelu_store(ch + 1, hw2);
      __syncthreads();                 // H[(ch+1)&1] ready; H[ch&1] free
    }
  }
  // epilogue: residual + bias, f32 store
#pragma unroll
  for (int i = 0; i < 4; ++i)
#pragma unroll
    for (int rg = 0; rg < 4; ++rg) {
      const long t = rbase + i * 16 + (ln >> 4) * 4 + rg;
#pragma unroll
      for (int j = 0; j < 4; ++j) {
        const int col = wv * 64 + j * 16 + (ln & 15);
        out[t * 256 + col] = x1[t * 256 + col] + acc[i][j][rg] + fb2[col];
      }
    }
}

extern "C" void kernel_launch(void* const* d_in, const int* in_sizes, int n_in,
                              void* d_out, int out_size, void* d_ws, size_t ws_size,
                              hipStream_t stream) {
  const float* x     = (const float*)d_in[0];
  const float* g1    = (const float*)d_in[1];
  const float* b1    = (const float*)d_in[2];
  const float* qw    = (const float*)d_in[3];
  const float* qb    = (const float*)d_in[4];
  const float* kvw   = (const float*)d_in[5];
  const float* kvb   = (const float*)d_in[6];
  const float* rpb   = (const float*)d_in[7];
  const float* projw = (const float*)d_in[8];
  const float* projb = (const float*)d_in[9];
  const float* g2    = (const float*)d_in[10];
  const float* b2    = (const float*)d_in[11];
  const float* fc1w  = (const float*)d_in[12];
  const float* fc1b  = (const float*)d_in[13];
  const float* fc2w  = (const float*)d_in[14];
  const float* fc2b  = (const float*)d_in[15];

  // Workspace: weights (bf16 B^T) + qkv only  (~203 MB total)
  unsigned short* wqkv  = (unsigned short*)d_ws;            // 196608
  unsigned short* wproj = wqkv + 196608;                     // 65536
  unsigned short* wfc1  = wproj + 65536;                     // 262144
  unsigned short* wfc2  = wfc1 + 262144;                     // 262144
  unsigned short* qkv   = wfc2 + 262144;                     // 100663296 (reused: x1 f32)
  float* x1 = (float*)qkv;
  // hw [131072][256] bf16 = first half of the f32 d_out buffer (scratch);
  // overwritten by attn-out, then fully overwritten by the final f32 store.
  unsigned short* hw = (unsigned short*)d_out;

  wt_transpose<<<256, 256, 0, stream>>>(qw, wqkv, 256, 256, 65536);
  wt_transpose<<<512, 256, 0, stream>>>(kvw, wqkv + 65536, 256, 512, 131072);
  wt_transpose<<<256, 256, 0, stream>>>(projw, wproj, 256, 256, 65536);
  wt_transpose<<<1024, 256, 0, stream>>>(fc1w, wfc1, 256, 1024, 262144);
  wt_transpose<<<1024, 256, 0, stream>>>(fc2w, wfc2, 1024, 256, 262144);

  ln1_win<<<32768, 256, 0, stream>>>(x, g1, b1, hw);
  gemm_qkv<<<dim3(6, 1024), 256, 0, stream>>>(hw, wqkv, qb, kvb, qkv);
  attn_win<<<8192, 64, 0, stream>>>(qkv, rpb, hw);           // hw now = attention output
  gemm_proj<<<dim3(2, 1024), 256, 0, stream>>>(hw, wproj, projb, x, x1);
  mlp_fused<<<2048, 256, 0, stream>>>(x1, g2, b2, wfc1, fc1b, wfc2, fc2b,
                                      (float*)d_out);
}